// Round 7
// baseline (274.903 us; speedup 1.0000x reference)
//
#include <hip/hip_runtime.h>

#define HWp 65536   // 256*256 pixels per plane

// ws layout (floats)
#define OFF_SH   0
#define OFF_SV   65536
#define OFF_XH   131072
#define OFF_XV   196608
#define OFF_WT   262144      // wt_g[c*64+o] = cw[o*64+c]      (4096)
#define OFF_A    266240      // A[d][o][c][j] fold of w3*cw     (24576)
#define OFF_CB   290816      // CB[d][j][o]  fold of w3*cb      (384)

__device__ __forceinline__ float fast_tanh(float v) {
    return 1.0f - 2.0f / (__expf(2.0f * v) + 1.0f);
}

// ---------------------------------------------------------------------------
// K1: strip-pool x (4 blocks per plane) + weight transpose + A/CB fold.
//   blocks 0..1023   : pool quarter-planes (Sv direct, Sh via atomicAdd)
//   block  1024      : wt_g transpose + CB fold
//   blocks 1025..1120: A[d][o][c][j] = sum_cm w3[o,cm,j] * cw[cm,c]
// ---------------------------------------------------------------------------
__global__ __launch_bounds__(256) void k_pool(const float* __restrict__ x,
                                              const float* __restrict__ cw,
                                              const float* __restrict__ cb,
                                              const float* __restrict__ chw,
                                              const float* __restrict__ cvw,
                                              float* __restrict__ ws) {
    const int bid = blockIdx.x;
    const int t   = threadIdx.x;

    if (bid >= 1025) {                        // ---- A fold ----
        const int idx = (bid - 1025) * 256 + t;      // [0, 24576)
        const int d   = idx / 12288;
        const int r   = idx - d * 12288;             // o*192 + c*3 + j
        const int o   = r / 192;
        const int rc  = r - o * 192;
        const int c   = rc / 3;
        const int j   = rc - c * 3;
        const float* w3 = d ? cvw : chw;
        float acc = 0.f;
        #pragma unroll 8
        for (int cm = 0; cm < 64; ++cm)
            acc += w3[o * 192 + cm * 3 + j] * cw[cm * 64 + c];
        ws[OFF_A + idx] = acc;
        return;
    }
    if (bid == 1024) {                        // ---- transpose + CB ----
        #pragma unroll
        for (int k = t; k < 4096; k += 256)
            ws[OFF_WT + k] = cw[(k & 63) * 64 + (k >> 6)];
        for (int k = t; k < 384; k += 256) {  // CB[d*192 + j*64 + o]
            const int d = k / 192;
            const int j = (k - d * 192) >> 6;
            const int o = k & 63;
            const float* w3 = d ? cvw : chw;
            float acc = 0.f;
            #pragma unroll 8
            for (int cm = 0; cm < 64; ++cm)
                acc += w3[o * 192 + cm * 3 + j] * cb[cm];
            ws[OFF_CB + k] = acc;
        }
        return;
    }

    // ---- pool quarter ----
    __shared__ float rowpart[64 * 65];        // [row_local][w4], pad 65
    __shared__ float colpart[4 * 256];
    const int bc = bid >> 2;                  // b*64+c
    const int q  = bid & 3;
    const float* plane = x + (size_t)bc * HWp + q * 64 * 256;
    const int w4 = t & 63;
    const int hg = t >> 6;

    float4 cacc = make_float4(0.f, 0.f, 0.f, 0.f);
    #pragma unroll 4
    for (int hh = 0; hh < 16; ++hh) {
        const int hl = hg * 16 + hh;
        const float4 v = *reinterpret_cast<const float4*>(plane + hl * 256 + w4 * 4);
        cacc.x += v.x; cacc.y += v.y; cacc.z += v.z; cacc.w += v.w;
        rowpart[hl * 65 + w4] = v.x + v.y + v.z + v.w;
    }
    *reinterpret_cast<float4*>(&colpart[hg * 256 + w4 * 4]) = cacc;
    __syncthreads();

    // row sums: 4 threads per row
    const int r   = t >> 2;
    const int seg = t & 3;
    float s = 0.f;
    #pragma unroll
    for (int i = 0; i < 16; ++i) s += rowpart[r * 65 + seg * 16 + i];
    s += __shfl_xor(s, 1, 64);
    s += __shfl_xor(s, 2, 64);
    if (seg == 0) ws[OFF_SV + bc * 256 + q * 64 + r] = s * (1.0f / 256.0f);

    const float cs = colpart[t] + colpart[256 + t] + colpart[512 + t] + colpart[768 + t];
    atomicAdd(&ws[OFF_SH + bc * 256 + t], cs * (1.0f / 256.0f));
}

// ---------------------------------------------------------------------------
// K2: strip conv — conv1 folded into conv3:
//   X[b,o,w] = sum_c' sum_j A[d,o,c',j]*S[c'][w+j-1]  + sum_{j in-b} CB[d,j,o]
// ---------------------------------------------------------------------------
__global__ __launch_bounds__(256) void k_strip(float* __restrict__ ws) {
    const int bid = blockIdx.x;
    const int w   = threadIdx.x & 255;
    const int o   = bid & 63;                  // SGPR-derived: uniform
    const int b   = (bid >> 6) & 3;
    const int d   = bid >> 8;
    const float* S  = ws + (d ? OFF_SV : OFF_SH) + b * 64 * 256;
    const float* Ad = ws + OFF_A + d * 12288 + o * 192;
    const float* CBd = ws + OFF_CB + d * 192;

    float acc = CBd[64 + o];
    if (w > 0)   acc += CBd[o];
    if (w < 255) acc += CBd[128 + o];
    #pragma unroll 8
    for (int c = 0; c < 64; ++c) {
        const float* sp = S + c * 256;
        const float a0 = Ad[c * 3 + 0];
        const float a1 = Ad[c * 3 + 1];
        const float a2 = Ad[c * 3 + 2];
        const float v0 = (w >= 1)   ? sp[w - 1] : 0.f;
        const float v1 = sp[w];
        const float v2 = (w <= 254) ? sp[w + 1] : 0.f;
        acc += a0 * v0 + a1 * v1 + a2 * v2;
    }
    ws[(d ? OFF_XV : OFF_XH) + (b * 64 + o) * 256 + w] = acc;
}

// ---------------------------------------------------------------------------
// K3 v3: fused per-pixel-kernel + 3x3 gather + 1x1 GEMM.
// vs v2: weights via SGPR s_load from pre-transposed wt_g (no wt LDS),
// LDS 37.9 -> 21.5KB -> 7 blocks/CU (87% occupancy cap).
// ---------------------------------------------------------------------------
__global__ __launch_bounds__(256, 7) void k_fused(const float* __restrict__ x,
                                                  const float* __restrict__ ws,
                                                  const float* __restrict__ cb,
                                                  const float* __restrict__ fw,
                                                  const float* __restrict__ fb,
                                                  float* __restrict__ out) {
    __shared__ __align__(16) float zl[32 * 128];      // 16KB  z[c_local][px]
    __shared__ __align__(16) float kernl[10 * 128];   // 5KB   rows 0-8 kern, row 9 kin

    const int lg   = (blockIdx.x & 7) * 256 + (blockIdx.x >> 3);  // XCD swizzle
    const int half = lg & 1;
    const int h    = (lg >> 1) & 255;                 // uniform in block
    const int b    = lg >> 9;
    const int w0   = half * 128;
    const int tid  = threadIdx.x;
    const float* XHb = ws + OFF_XH + b * 64 * 256;
    const float* XVb = ws + OFF_XV + b * 64 * 256;
    const float* wt_g = ws + OFF_WT;

    // ---- phase 0: per-pixel 9-tap kernel (+kin) from strip features ----
    if (tid < 128) {
        const int w = w0 + tid;
        float k9[9];
        #pragma unroll
        for (int o = 0; o < 9; ++o) k9[o] = fb[o];
        #pragma unroll 8
        for (int c = 0; c < 64; ++c) {
            const float s = XHb[c * 256 + w] + XVb[c * 256 + h];
            const float a = s > 0.f ? s : 0.2f * s;
            #pragma unroll
            for (int o = 0; o < 9; ++o) k9[o] += fw[o * 64 + c] * a;
        }
        float kt[9];
        #pragma unroll
        for (int o = 0; o < 9; ++o) {
            kt[o] = fast_tanh(k9[o]);
            kernl[o * 128 + tid] = kt[o];
        }
        const float m0 = (w >= 1)   ? 1.f : 0.f;
        const float m2 = (w <= 254) ? 1.f : 0.f;
        const float r0 = (h >= 1)   ? 1.f : 0.f;
        const float r2 = (h <= 254) ? 1.f : 0.f;
        float kin = 0.f;
        kin += r0 * (kt[0] * m0 + kt[1] + kt[2] * m2);
        kin +=      (kt[3] * m0 + kt[4] + kt[5] * m2);
        kin += r2 * (kt[6] * m0 + kt[7] + kt[8] * m2);
        kernl[9 * 128 + tid] = kin;
    }
    __syncthreads();

    // ---- setup ----
    const int g   = tid & 31;                  // px4 group
    const int c0  = tid >> 5;                  // channel sub-lane (0..7)
    const int gg  = half * 32 + g;             // global float4 column
    const int ggL = (gg > 0)  ? gg - 1 : 0;
    const int ggR = (gg < 63) ? gg + 1 : 63;
    const float mL = (gg == 0)  ? 0.f : 1.f;
    const float mR = (gg == 63) ? 0.f : 1.f;
    const bool rv0 = (h > 0);
    const bool rv2 = (h < 255);
    const float* xb = x + (size_t)b * 64 * HWp;

    const int og  = tid >> 6;
    const int po  = tid & 63;
    const int o0u = __builtin_amdgcn_readfirstlane(og * 16);  // SGPR
    float2 acc[16];
    #pragma unroll
    for (int i = 0; i < 16; ++i) acc[i] = make_float2(0.f, 0.f);

    #pragma unroll
    for (int chalf = 0; chalf < 2; ++chalf) {
        // per-px4 kernel taps (reload per chalf to limit VGPR pressure)
        float4 kr[9];
        #pragma unroll
        for (int q = 0; q < 9; ++q)
            kr[q] = *reinterpret_cast<const float4*>(&kernl[q * 128 + g * 4]);

        // ---- phase 1: z for 32 channels into zl ----
        #pragma unroll
        for (int it = 0; it < 4; ++it) {
            const int cl = it * 8 + c0;
            const int c  = chalf * 32 + cl;
            const float* rowm = xb + (size_t)c * HWp + h * 256;
            float4 z = make_float4(0.f, 0.f, 0.f, 0.f);
            #define ROW3(rp, ka, kb_, kc) { \
                const float4 vM = *reinterpret_cast<const float4*>((rp) + gg  * 4); \
                const float4 vL = *reinterpret_cast<const float4*>((rp) + ggL * 4); \
                const float4 vR = *reinterpret_cast<const float4*>((rp) + ggR * 4); \
                const float xl = vL.w * mL; \
                const float xr = vR.x * mR; \
                z.x += (ka).x * xl   + (kb_).x * vM.x + (kc).x * vM.y; \
                z.y += (ka).y * vM.x + (kb_).y * vM.y + (kc).y * vM.z; \
                z.z += (ka).z * vM.y + (kb_).z * vM.z + (kc).z * vM.w; \
                z.w += (ka).w * vM.z + (kb_).w * vM.w + (kc).w * xr;   }
            if (rv0) ROW3(rowm - 256, kr[0], kr[1], kr[2]);
            ROW3(rowm,       kr[3], kr[4], kr[5]);
            if (rv2) ROW3(rowm + 256, kr[6], kr[7], kr[8]);
            #undef ROW3
            *reinterpret_cast<float4*>(&zl[cl * 128 + g * 4]) = z;
        }
        __syncthreads();

        // ---- phase 2: partial GEMM; weights via uniform s_load ----
        const float* wg = wt_g + chalf * 32 * 64 + o0u;
        #pragma unroll 8
        for (int cl = 0; cl < 32; ++cl) {
            const float2 xv = *reinterpret_cast<const float2*>(&zl[cl * 128 + po * 2]);
            float wsv[16];
            #pragma unroll
            for (int i = 0; i < 16; ++i) wsv[i] = wg[cl * 64 + i];
            #pragma unroll
            for (int i = 0; i < 16; ++i) {
                acc[i].x += wsv[i] * xv.x;
                acc[i].y += wsv[i] * xv.y;
            }
        }
        if (chalf == 0) __syncthreads();
    }

    // ---- epilogue ----
    const float2 kin2 = *reinterpret_cast<const float2*>(&kernl[9 * 128 + po * 2]);
    float* ob = out + (size_t)b * 64 * HWp + h * 256 + w0;
    #pragma unroll
    for (int i = 0; i < 16; ++i) {
        const float bias = cb[o0u + i];
        float2 rres;
        rres.x = acc[i].x + bias * kin2.x;
        rres.y = acc[i].y + bias * kin2.y;
        *reinterpret_cast<float2*>(ob + (size_t)(o0u + i) * HWp + po * 2) = rres;
    }
}

// ---------------------------------------------------------------------------
extern "C" void kernel_launch(void* const* d_in, const int* in_sizes, int n_in,
                              void* d_out, int out_size, void* d_ws, size_t ws_size,
                              hipStream_t stream) {
    const float* x   = (const float*)d_in[0];
    const float* cw  = (const float*)d_in[1];   // (64,64)
    const float* cb  = (const float*)d_in[2];   // (64,)
    const float* chw = (const float*)d_in[3];   // (64,64,1,3)
    const float* cvw = (const float*)d_in[4];   // (64,64,3,1)
    const float* fw  = (const float*)d_in[5];   // (9,64)
    const float* fb  = (const float*)d_in[6];   // (9,)
    float* out = (float*)d_out;
    float* ws  = (float*)d_ws;

    // Sh accumulated via atomics -> zero it first (capture-legal memset)
    hipMemsetAsync(ws + OFF_SH, 0, 65536 * sizeof(float), stream);
    hipLaunchKernelGGL(k_pool,  dim3(1121), dim3(256), 0, stream, x, cw, cb, chw, cvw, ws);
    hipLaunchKernelGGL(k_strip, dim3(512),  dim3(256), 0, stream, ws);
    hipLaunchKernelGGL(k_fused, dim3(2048), dim3(256), 0, stream, x, ws, cb, fw, fb, out);
}

// Round 10
// 194.847 us; speedup vs baseline: 1.4109x; 1.4109x over previous
//
#include <hip/hip_runtime.h>

#define HWp 65536   // 256*256 pixels per plane

// ws layout (floats)
#define OFF_SH   0
#define OFF_SV   65536
#define OFF_XH   131072
#define OFF_XV   196608
#define OFF_WT   262144      // wt_g[c*64+o] = cw[o*64+c]      (4096)
#define OFF_A    266240      // A[d][o][c][j] fold of w3*cw     (24576)
#define OFF_CB   290816      // CB[d][j][o]  fold of w3*cb      (384)

__device__ __forceinline__ float fast_tanh(float v) {
    return 1.0f - 2.0f / (__expf(2.0f * v) + 1.0f);
}

// ---------------------------------------------------------------------------
// K1: strip-pool x (4 blocks per plane) + weight transpose + A/CB fold.
// ---------------------------------------------------------------------------
__global__ __launch_bounds__(256) void k_pool(const float* __restrict__ x,
                                              const float* __restrict__ cw,
                                              const float* __restrict__ cb,
                                              const float* __restrict__ chw,
                                              const float* __restrict__ cvw,
                                              float* __restrict__ ws) {
    const int bid = blockIdx.x;
    const int t   = threadIdx.x;

    if (bid >= 1025) {                        // ---- A fold ----
        const int idx = (bid - 1025) * 256 + t;      // [0, 24576)
        const int d   = idx / 12288;
        const int r   = idx - d * 12288;             // o*192 + c*3 + j
        const int o   = r / 192;
        const int rc  = r - o * 192;
        const int c   = rc / 3;
        const int j   = rc - c * 3;
        const float* w3 = d ? cvw : chw;
        float acc = 0.f;
        #pragma unroll 8
        for (int cm = 0; cm < 64; ++cm)
            acc += w3[o * 192 + cm * 3 + j] * cw[cm * 64 + c];
        ws[OFF_A + idx] = acc;
        return;
    }
    if (bid == 1024) {                        // ---- transpose + CB ----
        #pragma unroll
        for (int k = t; k < 4096; k += 256)
            ws[OFF_WT + k] = cw[(k & 63) * 64 + (k >> 6)];
        for (int k = t; k < 384; k += 256) {  // CB[d*192 + j*64 + o]
            const int d = k / 192;
            const int j = (k - d * 192) >> 6;
            const int o = k & 63;
            const float* w3 = d ? cvw : chw;
            float acc = 0.f;
            #pragma unroll 8
            for (int cm = 0; cm < 64; ++cm)
                acc += w3[o * 192 + cm * 3 + j] * cb[cm];
            ws[OFF_CB + k] = acc;
        }
        return;
    }

    // ---- pool quarter ----
    __shared__ float rowpart[64 * 65];        // [row_local][w4], pad 65
    __shared__ float colpart[4 * 256];
    const int bc = bid >> 2;                  // b*64+c
    const int q  = bid & 3;
    const float* plane = x + (size_t)bc * HWp + q * 64 * 256;
    const int w4 = t & 63;
    const int hg = t >> 6;

    float4 cacc = make_float4(0.f, 0.f, 0.f, 0.f);
    #pragma unroll 4
    for (int hh = 0; hh < 16; ++hh) {
        const int hl = hg * 16 + hh;
        const float4 v = *reinterpret_cast<const float4*>(plane + hl * 256 + w4 * 4);
        cacc.x += v.x; cacc.y += v.y; cacc.z += v.z; cacc.w += v.w;
        rowpart[hl * 65 + w4] = v.x + v.y + v.z + v.w;
    }
    *reinterpret_cast<float4*>(&colpart[hg * 256 + w4 * 4]) = cacc;
    __syncthreads();

    // row sums: 4 threads per row
    const int r   = t >> 2;
    const int seg = t & 3;
    float s = 0.f;
    #pragma unroll
    for (int i = 0; i < 16; ++i) s += rowpart[r * 65 + seg * 16 + i];
    s += __shfl_xor(s, 1, 64);
    s += __shfl_xor(s, 2, 64);
    if (seg == 0) ws[OFF_SV + bc * 256 + q * 64 + r] = s * (1.0f / 256.0f);

    const float cs = colpart[t] + colpart[256 + t] + colpart[512 + t] + colpart[768 + t];
    atomicAdd(&ws[OFF_SH + bc * 256 + t], cs * (1.0f / 256.0f));
}

// ---------------------------------------------------------------------------
// K2: strip conv — conv1 folded into conv3.
// ---------------------------------------------------------------------------
__global__ __launch_bounds__(256) void k_strip(float* __restrict__ ws) {
    const int bid = blockIdx.x;
    const int w   = threadIdx.x & 255;
    const int o   = bid & 63;
    const int b   = (bid >> 6) & 3;
    const int d   = bid >> 8;
    const float* S  = ws + (d ? OFF_SV : OFF_SH) + b * 64 * 256;
    const float* Ad = ws + OFF_A + d * 12288 + o * 192;
    const float* CBd = ws + OFF_CB + d * 192;

    float acc = CBd[64 + o];
    if (w > 0)   acc += CBd[o];
    if (w < 255) acc += CBd[128 + o];
    #pragma unroll 8
    for (int c = 0; c < 64; ++c) {
        const float* sp = S + c * 256;
        const float a0 = Ad[c * 3 + 0];
        const float a1 = Ad[c * 3 + 1];
        const float a2 = Ad[c * 3 + 2];
        const float v0 = (w >= 1)   ? sp[w - 1] : 0.f;
        const float v1 = sp[w];
        const float v2 = (w <= 254) ? sp[w + 1] : 0.f;
        acc += a0 * v0 + a1 * v1 + a2 * v2;
    }
    ws[(d ? OFF_XV : OFF_XH) + (b * 64 + o) * 256 + w] = acc;
}

// ---------------------------------------------------------------------------
// K3 v4: fused per-pixel-kernel + 3x3 gather + 1x1 GEMM.
// vs v3: __launch_bounds__(256,4) — v3's (256,7) forced VGPR cap ~73 and the
// compiler spilled (~224B/thread round-trip = +112MB fetch AND write, VGPR=36
// reported, VALUBusy 30->18%). Cap 128 lets regalloc land ~64-80 regs with no
// scratch; occupancy is then LDS-capped at 7 blocks/CU (21.5KB each).
// kr[9] hoisted back outside chalf loop (v2-proven liveness pattern).
// ---------------------------------------------------------------------------
__global__ __launch_bounds__(256, 4) void k_fused(const float* __restrict__ x,
                                                  const float* __restrict__ ws,
                                                  const float* __restrict__ cb,
                                                  const float* __restrict__ fw,
                                                  const float* __restrict__ fb,
                                                  float* __restrict__ out) {
    __shared__ __align__(16) float zl[32 * 128];      // 16KB  z[c_local][px]
    __shared__ __align__(16) float kernl[10 * 128];   // 5KB   rows 0-8 kern, row 9 kin

    const int lg   = (blockIdx.x & 7) * 256 + (blockIdx.x >> 3);  // XCD swizzle
    const int half = lg & 1;
    const int h    = (lg >> 1) & 255;                 // uniform in block
    const int b    = lg >> 9;
    const int w0   = half * 128;
    const int tid  = threadIdx.x;
    const float* XHb = ws + OFF_XH + b * 64 * 256;
    const float* XVb = ws + OFF_XV + b * 64 * 256;
    const float* wt_g = ws + OFF_WT;

    // ---- phase 0: per-pixel 9-tap kernel (+kin) from strip features ----
    if (tid < 128) {
        const int w = w0 + tid;
        float k9[9];
        #pragma unroll
        for (int o = 0; o < 9; ++o) k9[o] = fb[o];
        #pragma unroll 8
        for (int c = 0; c < 64; ++c) {
            const float s = XHb[c * 256 + w] + XVb[c * 256 + h];
            const float a = s > 0.f ? s : 0.2f * s;
            #pragma unroll
            for (int o = 0; o < 9; ++o) k9[o] += fw[o * 64 + c] * a;
        }
        float kt[9];
        #pragma unroll
        for (int o = 0; o < 9; ++o) {
            kt[o] = fast_tanh(k9[o]);
            kernl[o * 128 + tid] = kt[o];
        }
        const float m0 = (w >= 1)   ? 1.f : 0.f;
        const float m2 = (w <= 254) ? 1.f : 0.f;
        const float r0 = (h >= 1)   ? 1.f : 0.f;
        const float r2 = (h <= 254) ? 1.f : 0.f;
        float kin = 0.f;
        kin += r0 * (kt[0] * m0 + kt[1] + kt[2] * m2);
        kin +=      (kt[3] * m0 + kt[4] + kt[5] * m2);
        kin += r2 * (kt[6] * m0 + kt[7] + kt[8] * m2);
        kernl[9 * 128 + tid] = kin;
    }
    __syncthreads();

    // ---- setup ----
    const int g   = tid & 31;                  // px4 group
    const int c0  = tid >> 5;                  // channel sub-lane (0..7)
    const int gg  = half * 32 + g;             // global float4 column
    const int ggL = (gg > 0)  ? gg - 1 : 0;
    const int ggR = (gg < 63) ? gg + 1 : 63;
    const float mL = (gg == 0)  ? 0.f : 1.f;
    const float mR = (gg == 63) ? 0.f : 1.f;
    const bool rv0 = (h > 0);
    const bool rv2 = (h < 255);
    const float* xb = x + (size_t)b * 64 * HWp;

    // per-px4 kernel taps, loaded once (v2-proven liveness)
    float4 kr[9];
    #pragma unroll
    for (int q = 0; q < 9; ++q)
        kr[q] = *reinterpret_cast<const float4*>(&kernl[q * 128 + g * 4]);

    const int og  = tid >> 6;
    const int po  = tid & 63;
    const int o0u = __builtin_amdgcn_readfirstlane(og * 16);  // SGPR
    float2 acc[16];
    #pragma unroll
    for (int i = 0; i < 16; ++i) acc[i] = make_float2(0.f, 0.f);

    #pragma unroll
    for (int chalf = 0; chalf < 2; ++chalf) {
        // ---- phase 1: z for 32 channels into zl ----
        #pragma unroll
        for (int it = 0; it < 4; ++it) {
            const int cl = it * 8 + c0;
            const int c  = chalf * 32 + cl;
            const float* rowm = xb + (size_t)c * HWp + h * 256;
            float4 z = make_float4(0.f, 0.f, 0.f, 0.f);
            #define ROW3(rp, ka, kb_, kc) { \
                const float4 vM = *reinterpret_cast<const float4*>((rp) + gg  * 4); \
                const float4 vL = *reinterpret_cast<const float4*>((rp) + ggL * 4); \
                const float4 vR = *reinterpret_cast<const float4*>((rp) + ggR * 4); \
                const float xl = vL.w * mL; \
                const float xr = vR.x * mR; \
                z.x += (ka).x * xl   + (kb_).x * vM.x + (kc).x * vM.y; \
                z.y += (ka).y * vM.x + (kb_).y * vM.y + (kc).y * vM.z; \
                z.z += (ka).z * vM.y + (kb_).z * vM.z + (kc).z * vM.w; \
                z.w += (ka).w * vM.z + (kb_).w * vM.w + (kc).w * xr;   }
            if (rv0) ROW3(rowm - 256, kr[0], kr[1], kr[2]);
            ROW3(rowm,       kr[3], kr[4], kr[5]);
            if (rv2) ROW3(rowm + 256, kr[6], kr[7], kr[8]);
            #undef ROW3
            *reinterpret_cast<float4*>(&zl[cl * 128 + g * 4]) = z;
        }
        __syncthreads();

        // ---- phase 2: partial GEMM; weights via uniform s_load ----
        const float* wg = wt_g + chalf * 32 * 64 + o0u;
        #pragma unroll 8
        for (int cl = 0; cl < 32; ++cl) {
            const float2 xv = *reinterpret_cast<const float2*>(&zl[cl * 128 + po * 2]);
            #pragma unroll
            for (int i = 0; i < 16; ++i) {
                const float wv = wg[cl * 64 + i];
                acc[i].x += wv * xv.x;
                acc[i].y += wv * xv.y;
            }
        }
        if (chalf == 0) __syncthreads();
    }

    // ---- epilogue ----
    const float2 kin2 = *reinterpret_cast<const float2*>(&kernl[9 * 128 + po * 2]);
    float* ob = out + (size_t)b * 64 * HWp + h * 256 + w0;
    #pragma unroll
    for (int i = 0; i < 16; ++i) {
        const float bias = cb[o0u + i];
        float2 rres;
        rres.x = acc[i].x + bias * kin2.x;
        rres.y = acc[i].y + bias * kin2.y;
        *reinterpret_cast<float2*>(ob + (size_t)(o0u + i) * HWp + po * 2) = rres;
    }
}

// ---------------------------------------------------------------------------
extern "C" void kernel_launch(void* const* d_in, const int* in_sizes, int n_in,
                              void* d_out, int out_size, void* d_ws, size_t ws_size,
                              hipStream_t stream) {
    const float* x   = (const float*)d_in[0];
    const float* cw  = (const float*)d_in[1];   // (64,64)
    const float* cb  = (const float*)d_in[2];   // (64,)
    const float* chw = (const float*)d_in[3];   // (64,64,1,3)
    const float* cvw = (const float*)d_in[4];   // (64,64,3,1)
    const float* fw  = (const float*)d_in[5];   // (9,64)
    const float* fb  = (const float*)d_in[6];   // (9,)
    float* out = (float*)d_out;
    float* ws  = (float*)d_ws;

    // Sh accumulated via atomics -> zero it first (capture-legal memset)
    hipMemsetAsync(ws + OFF_SH, 0, 65536 * sizeof(float), stream);
    hipLaunchKernelGGL(k_pool,  dim3(1121), dim3(256), 0, stream, x, cw, cb, chw, cvw, ws);
    hipLaunchKernelGGL(k_strip, dim3(512),  dim3(256), 0, stream, ws);
    hipLaunchKernelGGL(k_fused, dim3(2048), dim3(256), 0, stream, x, ws, cb, fw, fb, out);
}